// Round 11
// baseline (208.547 us; speedup 1.0000x reference)
//
#include <hip/hip_runtime.h>
#include <hip/hip_bf16.h>

// ---------------------------------------------------------------------------
// GAT encoder, 2 layers. Round 11: round-10 structure +
//  - rank pass with 4-way replicated counters (4x less same-address atomic
//    serialization), VPT=4 full-size grid
//  - scan_write converts replica counts to absolute bases (place stays
//    atomic-free); rank packs (local_rank<<2)|replica
//  - node gather: 4-edge unrolled groups (16 row loads in flight per wave)
// ---------------------------------------------------------------------------

#define NEG_SLOPE 0.2f
#define SCAN_SEG 2048
#define NREP 4

typedef __attribute__((ext_vector_type(8))) short bf16x8;
typedef __attribute__((ext_vector_type(4))) float f32x4;

__device__ __forceinline__ unsigned short f2bf(float v) {
    __hip_bfloat16 b = __float2bfloat16(v);
    return *reinterpret_cast<unsigned short*>(&b);
}
__device__ __forceinline__ float bf2f(unsigned short u) {
    __hip_bfloat16 b = *reinterpret_cast<__hip_bfloat16*>(&u);
    return __bfloat162float(b);
}

// ---- fused: x f32 -> bf16 copy + s,d row dots. One wave per node. ----
__global__ __launch_bounds__(256) void xprep_k(
    const float* __restrict__ x, const float* __restrict__ va,
    const float* __restrict__ vb, unsigned short* __restrict__ xbf,
    float* __restrict__ s, float* __restrict__ d, int N) {
    int w = (blockIdx.x * 256 + threadIdx.x) >> 6;
    int lane = threadIdx.x & 63;
    if (w >= N) return;
    float2 v = *(const float2*)(x + (size_t)w * 128 + lane * 2);
    ushort2 u;
    u.x = f2bf(v.x);
    u.y = f2bf(v.y);
    *(ushort2*)(xbf + (size_t)w * 128 + lane * 2) = u;
    float ss = v.x * va[lane * 2] + v.y * va[lane * 2 + 1];
    float dd = v.x * vb[lane * 2] + v.y * vb[lane * 2 + 1];
    #pragma unroll
    for (int off = 32; off; off >>= 1) {
        ss += __shfl_down(ss, off);
        dd += __shfl_down(dd, off);
    }
    if (lane == 0) { s[w] = ss; d[w] = dd; }
}

// ---- weight transpose: W[K][Nn] f32 -> WT [Nn][K] bf16 ----
__global__ __launch_bounds__(256) void wt_bf_k(
    const float* __restrict__ W, unsigned short* __restrict__ T, int K, int Nn) {
    int i = blockIdx.x * 256 + threadIdx.x;
    if (i >= K * Nn) return;
    int k = i / Nn, n = i - k * Nn;
    T[(size_t)n * K + k] = f2bf(W[i]);
}

// ---- plain bf16 MFMA GEMM: A[M][K] bf16 @ BT[NN][K] bf16 -> [M][NN] ----
// EPI=1: relu(acc+bias[col]) -> bf16. EPI=2: plain bf16.
template <int K, int NN, int EPI>
__global__ __launch_bounds__(256) void gemm_bf16(
    const unsigned short* __restrict__ A, const unsigned short* __restrict__ BT,
    unsigned short* __restrict__ C, const float* __restrict__ bias, int M) {
    constexpr int BK = 32, PAD = 8;
    __shared__ short As[128][BK + PAD];
    __shared__ short Bs[64][BK + PAD];
    const int tid = threadIdx.x;
    const int wv = tid >> 6;
    const int ln = tid & 63;
    const int row0 = blockIdx.x * 128;
    const int col0 = blockIdx.y * 64;

    f32x4 acc[2][4];
    #pragma unroll
    for (int m = 0; m < 2; ++m)
        #pragma unroll
        for (int n = 0; n < 4; ++n) acc[m][n] = {0.f, 0.f, 0.f, 0.f};

    const int l15 = ln & 15;
    const int kg = (ln >> 4) * 8;

    for (int k0 = 0; k0 < K; k0 += BK) {
        #pragma unroll
        for (int t = 0; t < 2; ++t) {
            int v = tid + t * 256;
            int r = v >> 2;
            int kc = (v & 3) * 8;
            bf16x8 val = {0, 0, 0, 0, 0, 0, 0, 0};
            int gr = row0 + r;
            if (gr < M)
                val = *(const bf16x8*)(A + (size_t)gr * K + k0 + kc);
            *(bf16x8*)(&As[r][kc]) = val;
        }
        {
            int c = tid >> 2;
            int kc = (tid & 3) * 8;
            *(bf16x8*)(&Bs[c][kc]) =
                *(const bf16x8*)(BT + (size_t)(col0 + c) * K + k0 + kc);
        }
        __syncthreads();

        bf16x8 ah[2], bh[4];
        #pragma unroll
        for (int m = 0; m < 2; ++m)
            ah[m] = *(const bf16x8*)&As[wv * 32 + m * 16 + l15][kg];
        #pragma unroll
        for (int n = 0; n < 4; ++n)
            bh[n] = *(const bf16x8*)&Bs[n * 16 + l15][kg];
        #pragma unroll
        for (int m = 0; m < 2; ++m)
            #pragma unroll
            for (int n = 0; n < 4; ++n)
                acc[m][n] = __builtin_amdgcn_mfma_f32_16x16x32_bf16(
                    ah[m], bh[n], acc[m][n], 0, 0, 0);
        __syncthreads();
    }

    // C/D layout: col=lane&15, row=(lane>>4)*4+reg
    const int crow = (ln >> 4) * 4;
    #pragma unroll
    for (int m = 0; m < 2; ++m) {
        #pragma unroll
        for (int n = 0; n < 4; ++n) {
            int gr0 = row0 + wv * 32 + m * 16 + crow;
            int gc = col0 + n * 16 + l15;
            #pragma unroll
            for (int q = 0; q < 4; ++q) {
                int gr = gr0 + q;
                if (gr >= M) continue;
                if constexpr (EPI == 1) {
                    float v = acc[m][n][q] + bias[gc];
                    v = fmaxf(v, 0.f);
                    C[(size_t)gr * NN + gc] = f2bf(v);
                } else {
                    C[(size_t)gr * NN + gc] = f2bf(acc[m][n][q]);
                }
            }
        }
    }
}

// ---- per-node dots (f32 source) ----
template <int F>
__global__ __launch_bounds__(256) void rowdot_k(
    const float* __restrict__ h, const float* __restrict__ va,
    const float* __restrict__ vb, float* __restrict__ s,
    float* __restrict__ d, int N) {
    int w = (blockIdx.x * 256 + threadIdx.x) >> 6;
    int lane = threadIdx.x & 63;
    if (w >= N) return;
    const float* hp = h + (size_t)w * F;
    float ss = 0.f, dd = 0.f;
    #pragma unroll
    for (int f = lane; f < F; f += 64) {
        float v = hp[f];
        ss += v * va[f];
        dd += v * vb[f];
    }
    #pragma unroll
    for (int off = 32; off; off >>= 1) {
        ss += __shfl_down(ss, off);
        dd += __shfl_down(dd, off);
    }
    if (lane == 0) { s[w] = ss; d[w] = dd; }
}

// ---- per-node dots (bf16 source, F=128) ----
__global__ __launch_bounds__(256) void rowdot_bf_k(
    const unsigned short* __restrict__ h, const float* __restrict__ va,
    const float* __restrict__ vb, float* __restrict__ s,
    float* __restrict__ d, int N) {
    int w = (blockIdx.x * 256 + threadIdx.x) >> 6;
    int lane = threadIdx.x & 63;
    if (w >= N) return;
    ushort2 u = *(const ushort2*)(h + (size_t)w * 128 + lane * 2);
    float v0 = bf2f(u.x), v1 = bf2f(u.y);
    float ss = v0 * va[lane * 2] + v1 * va[lane * 2 + 1];
    float dd = v0 * vb[lane * 2] + v1 * vb[lane * 2 + 1];
    #pragma unroll
    for (int off = 32; off; off >>= 1) {
        ss += __shfl_down(ss, off);
        dd += __shfl_down(dd, off);
    }
    if (lane == 0) { s[w] = ss; d[w] = dd; }
}

// ---- CSR pass A: replicated-counter rank. rank=(local<<2)|rep ----
#define RANK_VPT 4
__global__ __launch_bounds__(256) void rank_k(
    const int* __restrict__ dstE, int* __restrict__ cnt,
    int* __restrict__ rank, int E, int N, int stride) {
    const int i0 = blockIdx.x * 256 + threadIdx.x;
    const int rep = threadIdx.x & (NREP - 1);
    const int total = E + N;
    int idx[RANK_VPT], di[RANK_VPT], r[RANK_VPT];
    #pragma unroll
    for (int k = 0; k < RANK_VPT; ++k) {
        idx[k] = i0 + k * stride;
        if (idx[k] < total)
            di[k] = (idx[k] < E) ? dstE[idx[k]] : idx[k] - E;
    }
    #pragma unroll
    for (int k = 0; k < RANK_VPT; ++k)
        if (idx[k] < total) r[k] = atomicAdd(&cnt[rep * N + di[k]], 1);
    #pragma unroll
    for (int k = 0; k < RANK_VPT; ++k)
        if (idx[k] < total) rank[idx[k]] = (r[k] << 2) | rep;
}

// ---- CSR pass C: atomic-free placement via absolute replica bases ----
__global__ __launch_bounds__(256) void place_k(
    const int* __restrict__ srcE, const int* __restrict__ dstE,
    const int* __restrict__ base, const int* __restrict__ rank,
    int* __restrict__ ssrc, int E, int N) {
    long long i = (long long)blockIdx.x * 256 + threadIdx.x;
    if (i >= (long long)E + N) return;
    int si, di;
    if (i < E) { si = srcE[i]; di = dstE[i]; }
    else       { si = di = (int)(i - E); }
    int pk = rank[i];
    ssrc[base[(pk & 3) * N + di] + (pk >> 2)] = si;
}

// ---- 3-phase multi-block exclusive scan (over 4-replica totals) ----
__global__ __launch_bounds__(256) void scan_part_k(
    const int* __restrict__ cnt, int* __restrict__ part, int N) {
    __shared__ int wsum[4];
    const int base = blockIdx.x * SCAN_SEG;
    const int lim = min(base + SCAN_SEG, N);
    int s = 0;
    for (int i = base + threadIdx.x; i < lim; i += 256)
        s += cnt[i] + cnt[N + i] + cnt[2 * N + i] + cnt[3 * N + i];
    #pragma unroll
    for (int off = 32; off; off >>= 1) s += __shfl_down(s, off);
    if ((threadIdx.x & 63) == 0) wsum[threadIdx.x >> 6] = s;
    __syncthreads();
    if (threadIdx.x == 0) part[blockIdx.x] = wsum[0] + wsum[1] + wsum[2] + wsum[3];
}

__global__ void scan_offsets_k(int* __restrict__ part, int nseg,
                               int* __restrict__ rowptr, int N) {
    if (threadIdx.x == 0) {
        int run = 0;
        for (int i = 0; i < nseg; ++i) { int c = part[i]; part[i] = run; run += c; }
        rowptr[N] = run;
    }
}

// writes rowptr and converts cnt[r][i] into absolute base offsets
__global__ __launch_bounds__(256) void scan_write_k(
    int* __restrict__ cnt, int* __restrict__ rowptr,
    const int* __restrict__ part, int N) {
    __shared__ int wsum[4];
    const int tid = threadIdx.x;
    const int lane = tid & 63;
    const int wv = tid >> 6;
    const int tbase = blockIdx.x * SCAN_SEG + tid * 8;
    int local[8];
    int s = 0;
    #pragma unroll
    for (int q = 0; q < 8; ++q) {
        int idx = tbase + q;
        int tot = 0;
        if (idx < N)
            tot = cnt[idx] + cnt[N + idx] + cnt[2 * N + idx] + cnt[3 * N + idx];
        local[q] = s;
        s += tot;
    }
    int incl = s;
    #pragma unroll
    for (int off = 1; off < 64; off <<= 1) {
        int t = __shfl_up(incl, off);
        if (lane >= off) incl += t;
    }
    if (lane == 63) wsum[wv] = incl;
    __syncthreads();
    if (tid == 0) {
        int r = 0;
        #pragma unroll
        for (int i = 0; i < 4; ++i) { int c = wsum[i]; wsum[i] = r; r += c; }
    }
    __syncthreads();
    const int base = part[blockIdx.x] + wsum[wv] + (incl - s);
    #pragma unroll
    for (int q = 0; q < 8; ++q) {
        int idx = tbase + q;
        if (idx < N) {
            int pos = base + local[q];
            rowptr[idx] = pos;
            int c0 = cnt[idx], c1 = cnt[N + idx], c2 = cnt[2 * N + idx];
            cnt[idx] = pos;
            cnt[N + idx] = pos + c0;
            cnt[2 * N + idx] = pos + c0 + c1;
            cnt[3 * N + idx] = pos + c0 + c1 + c2;
        }
    }
}

// ---- fused softmax + weighted gather. One wave/node, 4 groups x 16 lanes,
// 4-edge unrolled. No max pass (logits bounded; softmax shift-invariant).
// OUTBF: write bf16 (aggx). else: f32 + bias (final output).
template <bool OUTBF>
__global__ __launch_bounds__(256) void node_gather_k(
    const int* __restrict__ rowptr, const int* __restrict__ ssrc,
    const float* __restrict__ s, const float* __restrict__ d,
    const unsigned short* __restrict__ hsrc, const float* __restrict__ bias,
    unsigned short* __restrict__ obf, float* __restrict__ outf, int N) {
    constexpr int F = 128, G = 4;
    const int node = blockIdx.x * 4 + (threadIdx.x >> 6);
    const int lane = threadIdx.x & 63;
    if (node >= N) return;
    const int beg = rowptr[node];
    const int end = rowptr[node + 1];
    const float dn = d[node];
    const int grp = lane >> 4;   // 0..3
    const int lr = lane & 15;    // 0..15

    float acc[8] = {};
    float zsum = 0.f;
    int j = beg + grp;
    // 4-edge unroll: all loads issued before any accumulation
    for (; j + 3 * G < end; j += 4 * G) {
        int sj0 = ssrc[j];
        int sj1 = ssrc[j + G];
        int sj2 = ssrc[j + 2 * G];
        int sj3 = ssrc[j + 3 * G];
        float e0 = s[sj0] + dn;
        float e1 = s[sj1] + dn;
        float e2 = s[sj2] + dn;
        float e3 = s[sj3] + dn;
        bf16x8 v0 = *(const bf16x8*)(hsrc + (size_t)sj0 * F + lr * 8);
        bf16x8 v1 = *(const bf16x8*)(hsrc + (size_t)sj1 * F + lr * 8);
        bf16x8 v2 = *(const bf16x8*)(hsrc + (size_t)sj2 * F + lr * 8);
        bf16x8 v3 = *(const bf16x8*)(hsrc + (size_t)sj3 * F + lr * 8);
        e0 = (e0 > 0.f) ? e0 : NEG_SLOPE * e0;
        e1 = (e1 > 0.f) ? e1 : NEG_SLOPE * e1;
        e2 = (e2 > 0.f) ? e2 : NEG_SLOPE * e2;
        e3 = (e3 > 0.f) ? e3 : NEG_SLOPE * e3;
        float x0 = __expf(e0);
        float x1 = __expf(e1);
        float x2 = __expf(e2);
        float x3 = __expf(e3);
        zsum += (x0 + x1) + (x2 + x3);
        #pragma unroll
        for (int q = 0; q < 8; ++q) {
            acc[q] += x0 * bf2f(((unsigned short*)&v0)[q]);
            acc[q] += x1 * bf2f(((unsigned short*)&v1)[q]);
            acc[q] += x2 * bf2f(((unsigned short*)&v2)[q]);
            acc[q] += x3 * bf2f(((unsigned short*)&v3)[q]);
        }
    }
    for (; j < end; j += G) {
        int sj = ssrc[j];
        float e = s[sj] + dn;
        e = (e > 0.f) ? e : NEG_SLOPE * e;
        float exj = __expf(e);
        zsum += exj;
        bf16x8 v = *(const bf16x8*)(hsrc + (size_t)sj * F + lr * 8);
        #pragma unroll
        for (int q = 0; q < 8; ++q)
            acc[q] += exj * bf2f(((unsigned short*)&v)[q]);
    }
    // reduce across the 4 groups (lanes with equal lr)
    #pragma unroll
    for (int off = 16; off < 64; off <<= 1) {
        zsum += __shfl_xor(zsum, off);
        #pragma unroll
        for (int q = 0; q < 8; ++q) acc[q] += __shfl_xor(acc[q], off);
    }
    const float inv = 1.f / zsum;

    if (lane < 16) {
        if constexpr (OUTBF) {
            bf16x8 w;
            #pragma unroll
            for (int q = 0; q < 8; ++q)
                ((unsigned short*)&w)[q] = f2bf(acc[q] * inv);
            *(bf16x8*)(obf + (size_t)node * F + lr * 8) = w;
        } else {
            float o[8];
            #pragma unroll
            for (int q = 0; q < 8; ++q)
                o[q] = acc[q] * inv + bias[lr * 8 + q];
            float* op = outf + (size_t)node * F + lr * 8;
            *(float4*)op = {o[0], o[1], o[2], o[3]};
            *(float4*)(op + 4) = {o[4], o[5], o[6], o[7]};
        }
    }
}

extern "C" void kernel_launch(void* const* d_in, const int* in_sizes, int n_in,
                              void* d_out, int out_size, void* d_ws, size_t ws_size,
                              hipStream_t stream) {
    const float* x      = (const float*)d_in[0];
    const int*   eidx   = (const int*)d_in[1];
    const float* W1     = (const float*)d_in[2];
    const float* a_src1 = (const float*)d_in[3];
    const float* a_dst1 = (const float*)d_in[4];
    const float* b1     = (const float*)d_in[5];
    const float* W2     = (const float*)d_in[6];
    const float* a_src2 = (const float*)d_in[7];
    const float* a_dst2 = (const float*)d_in[8];
    const float* b2     = (const float*)d_in[9];

    const int N = in_sizes[0] / 128;   // 50000
    const int E = in_sizes[1] / 2;     // 800000
    const int F_IN = 128, H = 256, F_OUT = 128;
    const int EA = E + N;

    const int* srcE = eidx;
    const int* dstE = eidx + E;

    // ---- workspace layout (~74 MB) ----
    unsigned short* xbf    = (unsigned short*)d_ws;                 // N*128 bf16
    unsigned short* aggx   = xbf + (size_t)N * F_IN;                // N*128 bf16
    unsigned short* g1     = aggx + (size_t)N * F_IN;               // N*256 bf16
    unsigned short* h2bf   = g1 + (size_t)N * H;                    // N*128 bf16
    float*          sbuf   = (float*)(h2bf + (size_t)N * F_OUT);    // N
    float*          dbuf   = sbuf + N;                              // N
    float*          w_s1   = dbuf + N;                              // 128
    float*          w_d1   = w_s1 + F_IN;                           // 128
    unsigned short* w1T    = (unsigned short*)(w_d1 + F_IN);        // 256*128
    unsigned short* w2T    = w1T + 32768;                           // 128*256
    int*            rowptr = (int*)(w2T + 32768);                   // N+1
    int*            cnt    = rowptr + (N + 1);                      // NREP*N
    int*            part   = cnt + NREP * N;                        // 32
    int*            ssrc   = part + 32;                             // E+N
    int*            rank   = ssrc + EA;                             // E+N

    float* out = (float*)d_out;

    // ---------------- CSR build ----------------
    {
        hipMemsetAsync(cnt, 0, (size_t)NREP * N * 4, stream);
        int stride = (EA + RANK_VPT - 1) / RANK_VPT;
        int rblocks = (stride + 255) / 256;
        stride = rblocks * 256;
        rank_k<<<rblocks, 256, 0, stream>>>(dstE, cnt, rank, E, N, stride);
        int nseg = (N + SCAN_SEG - 1) / SCAN_SEG;
        scan_part_k<<<nseg, 256, 0, stream>>>(cnt, part, N);
        scan_offsets_k<<<1, 64, 0, stream>>>(part, nseg, rowptr, N);
        scan_write_k<<<nseg, 256, 0, stream>>>(cnt, rowptr, part, N);
        int eb = (EA + 255) / 256;
        place_k<<<eb, 256, 0, stream>>>(srcE, dstE, cnt, rank, ssrc, E, N);
    }

    // ---------------- prep: projections + weight transposes ----------------
    rowdot_k<256><<<32, 256, 0, stream>>>(W1, a_src1, a_dst1, w_s1, w_d1, F_IN);
    wt_bf_k<<<(F_IN * H + 255) / 256, 256, 0, stream>>>(W1, w1T, F_IN, H);
    wt_bf_k<<<(H * F_OUT + 255) / 256, 256, 0, stream>>>(W2, w2T, H, F_OUT);

    // ---------------- layer 1: xprep -> gather(x) -> GEMM ----------------
    {
        int rb = (N * 64 + 255) / 256;
        xprep_k<<<rb, 256, 0, stream>>>(x, w_s1, w_d1, xbf, sbuf, dbuf, N);

        int nb = (N + 3) / 4;
        node_gather_k<true><<<nb, 256, 0, stream>>>(
            rowptr, ssrc, sbuf, dbuf, xbf, nullptr, aggx, nullptr, N);

        dim3 gg((N + 127) / 128, H / 64);
        gemm_bf16<128, 256, 1><<<gg, 256, 0, stream>>>(aggx, w1T, g1, b1, N);
    }

    // ---------------- layer 2: GEMM -> rowdot -> gather(h2) ----------------
    {
        dim3 gg((N + 127) / 128, F_OUT / 64);
        gemm_bf16<256, 128, 2><<<gg, 256, 0, stream>>>(g1, w2T, h2bf, nullptr, N);

        int rb = (N * 64 + 255) / 256;
        rowdot_bf_k<<<rb, 256, 0, stream>>>(h2bf, a_src2, a_dst2, sbuf, dbuf, N);

        int nb = (N + 3) / 4;
        node_gather_k<false><<<nb, 256, 0, stream>>>(
            rowptr, ssrc, sbuf, dbuf, h2bf, b2, nullptr, out, N);
    }
}

// Round 12
// 205.607 us; speedup vs baseline: 1.0143x; 1.0143x over previous
//
#include <hip/hip_runtime.h>
#include <hip/hip_bf16.h>

// ---------------------------------------------------------------------------
// GAT encoder, 2 layers. Round 12: best-of recombination.
//  - replica rank (4-way counters, VPT=4)        [round 11 — fixes contention]
//  - 2-edge-unrolled node gather                 [round 10 — best measured]
//  - batched atomic-free place (VPT=4)
//  - fused weight transposes (one dispatch)
// ---------------------------------------------------------------------------

#define NEG_SLOPE 0.2f
#define SCAN_SEG 2048
#define NREP 4

typedef __attribute__((ext_vector_type(8))) short bf16x8;
typedef __attribute__((ext_vector_type(4))) float f32x4;

__device__ __forceinline__ unsigned short f2bf(float v) {
    __hip_bfloat16 b = __float2bfloat16(v);
    return *reinterpret_cast<unsigned short*>(&b);
}
__device__ __forceinline__ float bf2f(unsigned short u) {
    __hip_bfloat16 b = *reinterpret_cast<__hip_bfloat16*>(&u);
    return __bfloat162float(b);
}

// ---- fused: x f32 -> bf16 copy + s,d row dots. One wave per node. ----
__global__ __launch_bounds__(256) void xprep_k(
    const float* __restrict__ x, const float* __restrict__ va,
    const float* __restrict__ vb, unsigned short* __restrict__ xbf,
    float* __restrict__ s, float* __restrict__ d, int N) {
    int w = (blockIdx.x * 256 + threadIdx.x) >> 6;
    int lane = threadIdx.x & 63;
    if (w >= N) return;
    float2 v = *(const float2*)(x + (size_t)w * 128 + lane * 2);
    ushort2 u;
    u.x = f2bf(v.x);
    u.y = f2bf(v.y);
    *(ushort2*)(xbf + (size_t)w * 128 + lane * 2) = u;
    float ss = v.x * va[lane * 2] + v.y * va[lane * 2 + 1];
    float dd = v.x * vb[lane * 2] + v.y * vb[lane * 2 + 1];
    #pragma unroll
    for (int off = 32; off; off >>= 1) {
        ss += __shfl_down(ss, off);
        dd += __shfl_down(dd, off);
    }
    if (lane == 0) { s[w] = ss; d[w] = dd; }
}

// ---- fused weight transposes: W1[128][256]->w1T[256][128],
//      W2[256][128]->w2T[128][256], both f32->bf16 ----
__global__ __launch_bounds__(256) void wt_both_k(
    const float* __restrict__ W1, const float* __restrict__ W2,
    unsigned short* __restrict__ w1T, unsigned short* __restrict__ w2T) {
    int i = blockIdx.x * 256 + threadIdx.x;
    if (i < 32768) {                 // W1: K=128, Nn=256
        int k = i >> 8, n = i & 255;
        w1T[n * 128 + k] = f2bf(W1[i]);
    } else {                         // W2: K=256, Nn=128
        int j = i - 32768;
        int k = j >> 7, n = j & 127;
        w2T[n * 256 + k] = f2bf(W2[j]);
    }
}

// ---- plain bf16 MFMA GEMM: A[M][K] bf16 @ BT[NN][K] bf16 -> [M][NN] ----
// EPI=1: relu(acc+bias[col]) -> bf16. EPI=2: plain bf16.
template <int K, int NN, int EPI>
__global__ __launch_bounds__(256) void gemm_bf16(
    const unsigned short* __restrict__ A, const unsigned short* __restrict__ BT,
    unsigned short* __restrict__ C, const float* __restrict__ bias, int M) {
    constexpr int BK = 32, PAD = 8;
    __shared__ short As[128][BK + PAD];
    __shared__ short Bs[64][BK + PAD];
    const int tid = threadIdx.x;
    const int wv = tid >> 6;
    const int ln = tid & 63;
    const int row0 = blockIdx.x * 128;
    const int col0 = blockIdx.y * 64;

    f32x4 acc[2][4];
    #pragma unroll
    for (int m = 0; m < 2; ++m)
        #pragma unroll
        for (int n = 0; n < 4; ++n) acc[m][n] = {0.f, 0.f, 0.f, 0.f};

    const int l15 = ln & 15;
    const int kg = (ln >> 4) * 8;

    for (int k0 = 0; k0 < K; k0 += BK) {
        #pragma unroll
        for (int t = 0; t < 2; ++t) {
            int v = tid + t * 256;
            int r = v >> 2;
            int kc = (v & 3) * 8;
            bf16x8 val = {0, 0, 0, 0, 0, 0, 0, 0};
            int gr = row0 + r;
            if (gr < M)
                val = *(const bf16x8*)(A + (size_t)gr * K + k0 + kc);
            *(bf16x8*)(&As[r][kc]) = val;
        }
        {
            int c = tid >> 2;
            int kc = (tid & 3) * 8;
            *(bf16x8*)(&Bs[c][kc]) =
                *(const bf16x8*)(BT + (size_t)(col0 + c) * K + k0 + kc);
        }
        __syncthreads();

        bf16x8 ah[2], bh[4];
        #pragma unroll
        for (int m = 0; m < 2; ++m)
            ah[m] = *(const bf16x8*)&As[wv * 32 + m * 16 + l15][kg];
        #pragma unroll
        for (int n = 0; n < 4; ++n)
            bh[n] = *(const bf16x8*)&Bs[n * 16 + l15][kg];
        #pragma unroll
        for (int m = 0; m < 2; ++m)
            #pragma unroll
            for (int n = 0; n < 4; ++n)
                acc[m][n] = __builtin_amdgcn_mfma_f32_16x16x32_bf16(
                    ah[m], bh[n], acc[m][n], 0, 0, 0);
        __syncthreads();
    }

    // C/D layout: col=lane&15, row=(lane>>4)*4+reg
    const int crow = (ln >> 4) * 4;
    #pragma unroll
    for (int m = 0; m < 2; ++m) {
        #pragma unroll
        for (int n = 0; n < 4; ++n) {
            int gr0 = row0 + wv * 32 + m * 16 + crow;
            int gc = col0 + n * 16 + l15;
            #pragma unroll
            for (int q = 0; q < 4; ++q) {
                int gr = gr0 + q;
                if (gr >= M) continue;
                if constexpr (EPI == 1) {
                    float v = acc[m][n][q] + bias[gc];
                    v = fmaxf(v, 0.f);
                    C[(size_t)gr * NN + gc] = f2bf(v);
                } else {
                    C[(size_t)gr * NN + gc] = f2bf(acc[m][n][q]);
                }
            }
        }
    }
}

// ---- per-node dots (f32 source) ----
template <int F>
__global__ __launch_bounds__(256) void rowdot_k(
    const float* __restrict__ h, const float* __restrict__ va,
    const float* __restrict__ vb, float* __restrict__ s,
    float* __restrict__ d, int N) {
    int w = (blockIdx.x * 256 + threadIdx.x) >> 6;
    int lane = threadIdx.x & 63;
    if (w >= N) return;
    const float* hp = h + (size_t)w * F;
    float ss = 0.f, dd = 0.f;
    #pragma unroll
    for (int f = lane; f < F; f += 64) {
        float v = hp[f];
        ss += v * va[f];
        dd += v * vb[f];
    }
    #pragma unroll
    for (int off = 32; off; off >>= 1) {
        ss += __shfl_down(ss, off);
        dd += __shfl_down(dd, off);
    }
    if (lane == 0) { s[w] = ss; d[w] = dd; }
}

// ---- per-node dots (bf16 source, F=128) ----
__global__ __launch_bounds__(256) void rowdot_bf_k(
    const unsigned short* __restrict__ h, const float* __restrict__ va,
    const float* __restrict__ vb, float* __restrict__ s,
    float* __restrict__ d, int N) {
    int w = (blockIdx.x * 256 + threadIdx.x) >> 6;
    int lane = threadIdx.x & 63;
    if (w >= N) return;
    ushort2 u = *(const ushort2*)(h + (size_t)w * 128 + lane * 2);
    float v0 = bf2f(u.x), v1 = bf2f(u.y);
    float ss = v0 * va[lane * 2] + v1 * va[lane * 2 + 1];
    float dd = v0 * vb[lane * 2] + v1 * vb[lane * 2 + 1];
    #pragma unroll
    for (int off = 32; off; off >>= 1) {
        ss += __shfl_down(ss, off);
        dd += __shfl_down(dd, off);
    }
    if (lane == 0) { s[w] = ss; d[w] = dd; }
}

// ---- CSR pass A: replicated-counter rank. rank=(local<<2)|rep ----
#define RANK_VPT 4
__global__ __launch_bounds__(256) void rank_k(
    const int* __restrict__ dstE, int* __restrict__ cnt,
    int* __restrict__ rank, int E, int N, int stride) {
    const int i0 = blockIdx.x * 256 + threadIdx.x;
    const int rep = threadIdx.x & (NREP - 1);
    const int total = E + N;
    int idx[RANK_VPT], di[RANK_VPT], r[RANK_VPT];
    #pragma unroll
    for (int k = 0; k < RANK_VPT; ++k) {
        idx[k] = i0 + k * stride;
        if (idx[k] < total)
            di[k] = (idx[k] < E) ? dstE[idx[k]] : idx[k] - E;
    }
    #pragma unroll
    for (int k = 0; k < RANK_VPT; ++k)
        if (idx[k] < total) r[k] = atomicAdd(&cnt[rep * N + di[k]], 1);
    #pragma unroll
    for (int k = 0; k < RANK_VPT; ++k)
        if (idx[k] < total) rank[idx[k]] = (r[k] << 2) | rep;
}

// ---- CSR pass C: batched atomic-free placement ----
#define PLACE_VPT 4
__global__ __launch_bounds__(256) void place_k(
    const int* __restrict__ srcE, const int* __restrict__ dstE,
    const int* __restrict__ base, const int* __restrict__ rank,
    int* __restrict__ ssrc, int E, int N, int stride) {
    const int i0 = blockIdx.x * 256 + threadIdx.x;
    const int total = E + N;
    int idx[PLACE_VPT], si[PLACE_VPT], di[PLACE_VPT], pk[PLACE_VPT];
    #pragma unroll
    for (int k = 0; k < PLACE_VPT; ++k) {
        idx[k] = i0 + k * stride;
        if (idx[k] < total) {
            if (idx[k] < E) { si[k] = srcE[idx[k]]; di[k] = dstE[idx[k]]; }
            else            { si[k] = di[k] = idx[k] - E; }
            pk[k] = rank[idx[k]];
        }
    }
    int pos[PLACE_VPT];
    #pragma unroll
    for (int k = 0; k < PLACE_VPT; ++k)
        if (idx[k] < total) pos[k] = base[(pk[k] & 3) * N + di[k]];
    #pragma unroll
    for (int k = 0; k < PLACE_VPT; ++k)
        if (idx[k] < total) ssrc[pos[k] + (pk[k] >> 2)] = si[k];
}

// ---- 3-phase multi-block exclusive scan (over 4-replica totals) ----
__global__ __launch_bounds__(256) void scan_part_k(
    const int* __restrict__ cnt, int* __restrict__ part, int N) {
    __shared__ int wsum[4];
    const int base = blockIdx.x * SCAN_SEG;
    const int lim = min(base + SCAN_SEG, N);
    int s = 0;
    for (int i = base + threadIdx.x; i < lim; i += 256)
        s += cnt[i] + cnt[N + i] + cnt[2 * N + i] + cnt[3 * N + i];
    #pragma unroll
    for (int off = 32; off; off >>= 1) s += __shfl_down(s, off);
    if ((threadIdx.x & 63) == 0) wsum[threadIdx.x >> 6] = s;
    __syncthreads();
    if (threadIdx.x == 0) part[blockIdx.x] = wsum[0] + wsum[1] + wsum[2] + wsum[3];
}

__global__ void scan_offsets_k(int* __restrict__ part, int nseg,
                               int* __restrict__ rowptr, int N) {
    if (threadIdx.x == 0) {
        int run = 0;
        for (int i = 0; i < nseg; ++i) { int c = part[i]; part[i] = run; run += c; }
        rowptr[N] = run;
    }
}

// writes rowptr and converts cnt[r][i] into absolute base offsets
__global__ __launch_bounds__(256) void scan_write_k(
    int* __restrict__ cnt, int* __restrict__ rowptr,
    const int* __restrict__ part, int N) {
    __shared__ int wsum[4];
    const int tid = threadIdx.x;
    const int lane = tid & 63;
    const int wv = tid >> 6;
    const int tbase = blockIdx.x * SCAN_SEG + tid * 8;
    int local[8];
    int s = 0;
    #pragma unroll
    for (int q = 0; q < 8; ++q) {
        int idx = tbase + q;
        int tot = 0;
        if (idx < N)
            tot = cnt[idx] + cnt[N + idx] + cnt[2 * N + idx] + cnt[3 * N + idx];
        local[q] = s;
        s += tot;
    }
    int incl = s;
    #pragma unroll
    for (int off = 1; off < 64; off <<= 1) {
        int t = __shfl_up(incl, off);
        if (lane >= off) incl += t;
    }
    if (lane == 63) wsum[wv] = incl;
    __syncthreads();
    if (tid == 0) {
        int r = 0;
        #pragma unroll
        for (int i = 0; i < 4; ++i) { int c = wsum[i]; wsum[i] = r; r += c; }
    }
    __syncthreads();
    const int base = part[blockIdx.x] + wsum[wv] + (incl - s);
    #pragma unroll
    for (int q = 0; q < 8; ++q) {
        int idx = tbase + q;
        if (idx < N) {
            int pos = base + local[q];
            rowptr[idx] = pos;
            int c0 = cnt[idx], c1 = cnt[N + idx], c2 = cnt[2 * N + idx];
            cnt[idx] = pos;
            cnt[N + idx] = pos + c0;
            cnt[2 * N + idx] = pos + c0 + c1;
            cnt[3 * N + idx] = pos + c0 + c1 + c2;
        }
    }
}

// ---- fused softmax + weighted gather. One wave/node, 4 groups x 16 lanes,
// 2-edge unrolled (round-10 best). No max pass.
// OUTBF: write bf16 (aggx). else: f32 + bias (final output).
template <bool OUTBF>
__global__ __launch_bounds__(256) void node_gather_k(
    const int* __restrict__ rowptr, const int* __restrict__ ssrc,
    const float* __restrict__ s, const float* __restrict__ d,
    const unsigned short* __restrict__ hsrc, const float* __restrict__ bias,
    unsigned short* __restrict__ obf, float* __restrict__ outf, int N) {
    constexpr int F = 128, G = 4;
    const int node = blockIdx.x * 4 + (threadIdx.x >> 6);
    const int lane = threadIdx.x & 63;
    if (node >= N) return;
    const int beg = rowptr[node];
    const int end = rowptr[node + 1];
    const float dn = d[node];
    const int grp = lane >> 4;   // 0..3
    const int lr = lane & 15;    // 0..15

    float acc[8] = {};
    float zsum = 0.f;
    int j = beg + grp;
    // pairs: both edges' loads issued before any accumulation
    for (; j + G < end; j += 2 * G) {
        int sj0 = ssrc[j];
        int sj1 = ssrc[j + G];
        float e0 = s[sj0] + dn;
        float e1 = s[sj1] + dn;
        bf16x8 v0 = *(const bf16x8*)(hsrc + (size_t)sj0 * F + lr * 8);
        bf16x8 v1 = *(const bf16x8*)(hsrc + (size_t)sj1 * F + lr * 8);
        e0 = (e0 > 0.f) ? e0 : NEG_SLOPE * e0;
        e1 = (e1 > 0.f) ? e1 : NEG_SLOPE * e1;
        float x0 = __expf(e0);
        float x1 = __expf(e1);
        zsum += x0 + x1;
        #pragma unroll
        for (int q = 0; q < 8; ++q) {
            acc[q] += x0 * bf2f(((unsigned short*)&v0)[q]);
            acc[q] += x1 * bf2f(((unsigned short*)&v1)[q]);
        }
    }
    if (j < end) {
        int sj = ssrc[j];
        float e = s[sj] + dn;
        e = (e > 0.f) ? e : NEG_SLOPE * e;
        float exj = __expf(e);
        zsum += exj;
        bf16x8 v = *(const bf16x8*)(hsrc + (size_t)sj * F + lr * 8);
        #pragma unroll
        for (int q = 0; q < 8; ++q)
            acc[q] += exj * bf2f(((unsigned short*)&v)[q]);
    }
    // reduce across the 4 groups (lanes with equal lr)
    #pragma unroll
    for (int off = 16; off < 64; off <<= 1) {
        zsum += __shfl_xor(zsum, off);
        #pragma unroll
        for (int q = 0; q < 8; ++q) acc[q] += __shfl_xor(acc[q], off);
    }
    const float inv = 1.f / zsum;

    if (lane < 16) {
        if constexpr (OUTBF) {
            bf16x8 w;
            #pragma unroll
            for (int q = 0; q < 8; ++q)
                ((unsigned short*)&w)[q] = f2bf(acc[q] * inv);
            *(bf16x8*)(obf + (size_t)node * F + lr * 8) = w;
        } else {
            float o[8];
            #pragma unroll
            for (int q = 0; q < 8; ++q)
                o[q] = acc[q] * inv + bias[lr * 8 + q];
            float* op = outf + (size_t)node * F + lr * 8;
            *(float4*)op = {o[0], o[1], o[2], o[3]};
            *(float4*)(op + 4) = {o[4], o[5], o[6], o[7]};
        }
    }
}

extern "C" void kernel_launch(void* const* d_in, const int* in_sizes, int n_in,
                              void* d_out, int out_size, void* d_ws, size_t ws_size,
                              hipStream_t stream) {
    const float* x      = (const float*)d_in[0];
    const int*   eidx   = (const int*)d_in[1];
    const float* W1     = (const float*)d_in[2];
    const float* a_src1 = (const float*)d_in[3];
    const float* a_dst1 = (const float*)d_in[4];
    const float* b1     = (const float*)d_in[5];
    const float* W2     = (const float*)d_in[6];
    const float* a_src2 = (const float*)d_in[7];
    const float* a_dst2 = (const float*)d_in[8];
    const float* b2     = (const float*)d_in[9];

    const int N = in_sizes[0] / 128;   // 50000
    const int E = in_sizes[1] / 2;     // 800000
    const int F_IN = 128, H = 256, F_OUT = 128;
    const int EA = E + N;

    const int* srcE = eidx;
    const int* dstE = eidx + E;

    // ---- workspace layout (~74 MB) ----
    unsigned short* xbf    = (unsigned short*)d_ws;                 // N*128 bf16
    unsigned short* aggx   = xbf + (size_t)N * F_IN;                // N*128 bf16
    unsigned short* g1     = aggx + (size_t)N * F_IN;               // N*256 bf16
    unsigned short* h2bf   = g1 + (size_t)N * H;                    // N*128 bf16
    float*          sbuf   = (float*)(h2bf + (size_t)N * F_OUT);    // N
    float*          dbuf   = sbuf + N;                              // N
    float*          w_s1   = dbuf + N;                              // 128
    float*          w_d1   = w_s1 + F_IN;                           // 128
    unsigned short* w1T    = (unsigned short*)(w_d1 + F_IN);        // 256*128
    unsigned short* w2T    = w1T + 32768;                           // 128*256
    int*            rowptr = (int*)(w2T + 32768);                   // N+1
    int*            cnt    = rowptr + (N + 1);                      // NREP*N
    int*            part   = cnt + NREP * N;                        // 32
    int*            ssrc   = part + 32;                             // E+N
    int*            rank   = ssrc + EA;                             // E+N

    float* out = (float*)d_out;

    // ---------------- CSR build ----------------
    {
        hipMemsetAsync(cnt, 0, (size_t)NREP * N * 4, stream);
        int stride = (EA + RANK_VPT - 1) / RANK_VPT;
        int rblocks = (stride + 255) / 256;
        stride = rblocks * 256;
        rank_k<<<rblocks, 256, 0, stream>>>(dstE, cnt, rank, E, N, stride);
        int nseg = (N + SCAN_SEG - 1) / SCAN_SEG;
        scan_part_k<<<nseg, 256, 0, stream>>>(cnt, part, N);
        scan_offsets_k<<<1, 64, 0, stream>>>(part, nseg, rowptr, N);
        scan_write_k<<<nseg, 256, 0, stream>>>(cnt, rowptr, part, N);
        place_k<<<rblocks, 256, 0, stream>>>(srcE, dstE, cnt, rank, ssrc, E, N, stride);
    }

    // ---------------- prep: projections + weight transposes ----------------
    rowdot_k<256><<<32, 256, 0, stream>>>(W1, a_src1, a_dst1, w_s1, w_d1, F_IN);
    wt_both_k<<<(65536 + 255) / 256, 256, 0, stream>>>(W1, W2, w1T, w2T);

    // ---------------- layer 1: xprep -> gather(x) -> GEMM ----------------
    {
        int rb = (N * 64 + 255) / 256;
        xprep_k<<<rb, 256, 0, stream>>>(x, w_s1, w_d1, xbf, sbuf, dbuf, N);

        int nb = (N + 3) / 4;
        node_gather_k<true><<<nb, 256, 0, stream>>>(
            rowptr, ssrc, sbuf, dbuf, xbf, nullptr, aggx, nullptr, N);

        dim3 gg((N + 127) / 128, H / 64);
        gemm_bf16<128, 256, 1><<<gg, 256, 0, stream>>>(aggx, w1T, g1, b1, N);
    }

    // ---------------- layer 2: GEMM -> rowdot -> gather(h2) ----------------
    {
        dim3 gg((N + 127) / 128, F_OUT / 64);
        gemm_bf16<256, 128, 2><<<gg, 256, 0, stream>>>(g1, w2T, h2bf, nullptr, N);

        int rb = (N * 64 + 255) / 256;
        rowdot_bf_k<<<rb, 256, 0, stream>>>(h2bf, a_src2, a_dst2, sbuf, dbuf, N);

        int nb = (N + 3) / 4;
        node_gather_k<false><<<nb, 256, 0, stream>>>(
            rowptr, ssrc, sbuf, dbuf, h2bf, b2, nullptr, out, N);
    }
}

// Round 13
// 191.310 us; speedup vs baseline: 1.0901x; 1.0747x over previous
//
#include <hip/hip_runtime.h>
#include <hip/hip_bf16.h>

// ---------------------------------------------------------------------------
// GAT encoder, 2 layers. Round 13: round-12 structure +
//  - BN=128 GEMM tiles (A re-read halved; GEMM2 reads A once)
//  - GEMM2 epilogue computes layer-2 rowdots in-register (rowdot_bf pass gone)
//  - single fused weight-prep kernel
// 12 dispatches total.
// ---------------------------------------------------------------------------

#define NEG_SLOPE 0.2f
#define SCAN_SEG 2048
#define NREP 4

typedef __attribute__((ext_vector_type(8))) short bf16x8;
typedef __attribute__((ext_vector_type(4))) float f32x4;

__device__ __forceinline__ unsigned short f2bf(float v) {
    __hip_bfloat16 b = __float2bfloat16(v);
    return *reinterpret_cast<unsigned short*>(&b);
}
__device__ __forceinline__ float bf2f(unsigned short u) {
    __hip_bfloat16 b = *reinterpret_cast<__hip_bfloat16*>(&u);
    return __bfloat162float(b);
}

// ---- fused: x f32 -> bf16 copy + s,d row dots. One wave per node. ----
__global__ __launch_bounds__(256) void xprep_k(
    const float* __restrict__ x, const float* __restrict__ va,
    const float* __restrict__ vb, unsigned short* __restrict__ xbf,
    float* __restrict__ s, float* __restrict__ d, int N) {
    int w = (blockIdx.x * 256 + threadIdx.x) >> 6;
    int lane = threadIdx.x & 63;
    if (w >= N) return;
    float2 v = *(const float2*)(x + (size_t)w * 128 + lane * 2);
    ushort2 u;
    u.x = f2bf(v.x);
    u.y = f2bf(v.y);
    *(ushort2*)(xbf + (size_t)w * 128 + lane * 2) = u;
    float ss = v.x * va[lane * 2] + v.y * va[lane * 2 + 1];
    float dd = v.x * vb[lane * 2] + v.y * vb[lane * 2 + 1];
    #pragma unroll
    for (int off = 32; off; off >>= 1) {
        ss += __shfl_down(ss, off);
        dd += __shfl_down(dd, off);
    }
    if (lane == 0) { s[w] = ss; d[w] = dd; }
}

// ---- fused weight prep: transposes (f32->bf16) + W1 projection dots ----
// blocks 0..127: W1 transpose; 128..255: W2 transpose; 256..287: proj dots.
__global__ __launch_bounds__(256) void wprep_k(
    const float* __restrict__ W1, const float* __restrict__ W2,
    const float* __restrict__ a_src1, const float* __restrict__ a_dst1,
    unsigned short* __restrict__ w1T, unsigned short* __restrict__ w2T,
    float* __restrict__ w_s1, float* __restrict__ w_d1) {
    const int b = blockIdx.x;
    if (b < 128) {                       // W1[128][256] -> w1T[256][128]
        int i = b * 256 + threadIdx.x;
        int k = i >> 8, n = i & 255;
        w1T[n * 128 + k] = f2bf(W1[i]);
    } else if (b < 256) {                // W2[256][128] -> w2T[128][256]
        int j = (b - 128) * 256 + threadIdx.x;
        int k = j >> 7, n = j & 127;
        w2T[n * 256 + k] = f2bf(W2[j]);
    } else {                             // w_s1[f]=W1[f]·a_src1, w_d1 likewise
        int w = ((b - 256) * 256 + threadIdx.x) >> 6;  // 0..127
        int lane = threadIdx.x & 63;
        const float* row = W1 + (size_t)w * 256;
        float ss = 0.f, dd = 0.f;
        #pragma unroll
        for (int f = lane; f < 256; f += 64) {
            float v = row[f];
            ss += v * a_src1[f];
            dd += v * a_dst1[f];
        }
        #pragma unroll
        for (int off = 32; off; off >>= 1) {
            ss += __shfl_down(ss, off);
            dd += __shfl_down(dd, off);
        }
        if (lane == 0) { w_s1[w] = ss; w_d1[w] = dd; }
    }
}

// ---- bf16 MFMA GEMM, BM=128 BN=128 BK=32, 4 waves (32 rows x 128 cols each).
// EPI=1: relu(acc+bias[col]) -> bf16 C. EPI=2: bf16 C + in-register rowdots
//        sOut[row]=C_row·va, dOut[row]=C_row·vb (BN==NN: full rows in block).
template <int K, int NN, int EPI>
__global__ __launch_bounds__(256) void gemm_bf16(
    const unsigned short* __restrict__ A, const unsigned short* __restrict__ BT,
    unsigned short* __restrict__ C, const float* __restrict__ bias,
    const float* __restrict__ va, const float* __restrict__ vb,
    float* __restrict__ sOut, float* __restrict__ dOut, int M) {
    constexpr int BK = 32, PAD = 8;
    __shared__ short As[128][BK + PAD];
    __shared__ short Bs[128][BK + PAD];
    const int tid = threadIdx.x;
    const int wv = tid >> 6;
    const int ln = tid & 63;
    const int row0 = blockIdx.x * 128;
    const int col0 = blockIdx.y * 128;

    f32x4 acc[2][8];
    #pragma unroll
    for (int m = 0; m < 2; ++m)
        #pragma unroll
        for (int n = 0; n < 8; ++n) acc[m][n] = {0.f, 0.f, 0.f, 0.f};

    const int l15 = ln & 15;
    const int kg = (ln >> 4) * 8;

    for (int k0 = 0; k0 < K; k0 += BK) {
        #pragma unroll
        for (int t = 0; t < 2; ++t) {
            int v = tid + t * 256;
            int r = v >> 2;
            int kc = (v & 3) * 8;
            bf16x8 val = {0, 0, 0, 0, 0, 0, 0, 0};
            int gr = row0 + r;
            if (gr < M)
                val = *(const bf16x8*)(A + (size_t)gr * K + k0 + kc);
            *(bf16x8*)(&As[r][kc]) = val;
        }
        #pragma unroll
        for (int t = 0; t < 2; ++t) {
            int v = tid + t * 256;
            int c = v >> 2;
            int kc = (v & 3) * 8;
            *(bf16x8*)(&Bs[c][kc]) =
                *(const bf16x8*)(BT + (size_t)(col0 + c) * K + k0 + kc);
        }
        __syncthreads();

        bf16x8 ah[2], bh[8];
        #pragma unroll
        for (int m = 0; m < 2; ++m)
            ah[m] = *(const bf16x8*)&As[wv * 32 + m * 16 + l15][kg];
        #pragma unroll
        for (int n = 0; n < 8; ++n)
            bh[n] = *(const bf16x8*)&Bs[n * 16 + l15][kg];
        #pragma unroll
        for (int m = 0; m < 2; ++m)
            #pragma unroll
            for (int n = 0; n < 8; ++n)
                acc[m][n] = __builtin_amdgcn_mfma_f32_16x16x32_bf16(
                    ah[m], bh[n], acc[m][n], 0, 0, 0);
        __syncthreads();
    }

    // C/D layout: col=lane&15, row=(lane>>4)*4+reg
    const int crow = (ln >> 4) * 4;
    #pragma unroll
    for (int m = 0; m < 2; ++m) {
        #pragma unroll
        for (int q = 0; q < 4; ++q) {
            int gr = row0 + wv * 32 + m * 16 + crow + q;
            if (gr >= M) continue;
            if constexpr (EPI == 1) {
                #pragma unroll
                for (int n = 0; n < 8; ++n) {
                    int gc = col0 + n * 16 + l15;
                    float v = acc[m][n][q] + bias[gc];
                    v = fmaxf(v, 0.f);
                    C[(size_t)gr * NN + gc] = f2bf(v);
                }
            } else {
                float sp = 0.f, dp = 0.f;
                #pragma unroll
                for (int n = 0; n < 8; ++n) {
                    int gc = n * 16 + l15;
                    float v = acc[m][n][q];
                    C[(size_t)gr * NN + gc] = f2bf(v);
                    sp += v * va[gc];
                    dp += v * vb[gc];
                }
                #pragma unroll
                for (int off = 1; off < 16; off <<= 1) {
                    sp += __shfl_xor(sp, off);
                    dp += __shfl_xor(dp, off);
                }
                if (l15 == 0) { sOut[gr] = sp; dOut[gr] = dp; }
            }
        }
    }
}

// ---- CSR pass A: replicated-counter rank. rank=(local<<2)|rep ----
#define RANK_VPT 4
__global__ __launch_bounds__(256) void rank_k(
    const int* __restrict__ dstE, int* __restrict__ cnt,
    int* __restrict__ rank, int E, int N, int stride) {
    const int i0 = blockIdx.x * 256 + threadIdx.x;
    const int rep = threadIdx.x & (NREP - 1);
    const int total = E + N;
    int idx[RANK_VPT], di[RANK_VPT], r[RANK_VPT];
    #pragma unroll
    for (int k = 0; k < RANK_VPT; ++k) {
        idx[k] = i0 + k * stride;
        if (idx[k] < total)
            di[k] = (idx[k] < E) ? dstE[idx[k]] : idx[k] - E;
    }
    #pragma unroll
    for (int k = 0; k < RANK_VPT; ++k)
        if (idx[k] < total) r[k] = atomicAdd(&cnt[rep * N + di[k]], 1);
    #pragma unroll
    for (int k = 0; k < RANK_VPT; ++k)
        if (idx[k] < total) rank[idx[k]] = (r[k] << 2) | rep;
}

// ---- CSR pass C: batched atomic-free placement ----
#define PLACE_VPT 4
__global__ __launch_bounds__(256) void place_k(
    const int* __restrict__ srcE, const int* __restrict__ dstE,
    const int* __restrict__ base, const int* __restrict__ rank,
    int* __restrict__ ssrc, int E, int N, int stride) {
    const int i0 = blockIdx.x * 256 + threadIdx.x;
    const int total = E + N;
    int idx[PLACE_VPT], si[PLACE_VPT], di[PLACE_VPT], pk[PLACE_VPT];
    #pragma unroll
    for (int k = 0; k < PLACE_VPT; ++k) {
        idx[k] = i0 + k * stride;
        if (idx[k] < total) {
            if (idx[k] < E) { si[k] = srcE[idx[k]]; di[k] = dstE[idx[k]]; }
            else            { si[k] = di[k] = idx[k] - E; }
            pk[k] = rank[idx[k]];
        }
    }
    int pos[PLACE_VPT];
    #pragma unroll
    for (int k = 0; k < PLACE_VPT; ++k)
        if (idx[k] < total) pos[k] = base[(pk[k] & 3) * N + di[k]];
    #pragma unroll
    for (int k = 0; k < PLACE_VPT; ++k)
        if (idx[k] < total) ssrc[pos[k] + (pk[k] >> 2)] = si[k];
}

// ---- 3-phase multi-block exclusive scan (over 4-replica totals) ----
__global__ __launch_bounds__(256) void scan_part_k(
    const int* __restrict__ cnt, int* __restrict__ part, int N) {
    __shared__ int wsum[4];
    const int base = blockIdx.x * SCAN_SEG;
    const int lim = min(base + SCAN_SEG, N);
    int s = 0;
    for (int i = base + threadIdx.x; i < lim; i += 256)
        s += cnt[i] + cnt[N + i] + cnt[2 * N + i] + cnt[3 * N + i];
    #pragma unroll
    for (int off = 32; off; off >>= 1) s += __shfl_down(s, off);
    if ((threadIdx.x & 63) == 0) wsum[threadIdx.x >> 6] = s;
    __syncthreads();
    if (threadIdx.x == 0) part[blockIdx.x] = wsum[0] + wsum[1] + wsum[2] + wsum[3];
}

__global__ void scan_offsets_k(int* __restrict__ part, int nseg,
                               int* __restrict__ rowptr, int N) {
    if (threadIdx.x == 0) {
        int run = 0;
        for (int i = 0; i < nseg; ++i) { int c = part[i]; part[i] = run; run += c; }
        rowptr[N] = run;
    }
}

// writes rowptr and converts cnt[r][i] into absolute base offsets
__global__ __launch_bounds__(256) void scan_write_k(
    int* __restrict__ cnt, int* __restrict__ rowptr,
    const int* __restrict__ part, int N) {
    __shared__ int wsum[4];
    const int tid = threadIdx.x;
    const int lane = tid & 63;
    const int wv = tid >> 6;
    const int tbase = blockIdx.x * SCAN_SEG + tid * 8;
    int local[8];
    int s = 0;
    #pragma unroll
    for (int q = 0; q < 8; ++q) {
        int idx = tbase + q;
        int tot = 0;
        if (idx < N)
            tot = cnt[idx] + cnt[N + idx] + cnt[2 * N + idx] + cnt[3 * N + idx];
        local[q] = s;
        s += tot;
    }
    int incl = s;
    #pragma unroll
    for (int off = 1; off < 64; off <<= 1) {
        int t = __shfl_up(incl, off);
        if (lane >= off) incl += t;
    }
    if (lane == 63) wsum[wv] = incl;
    __syncthreads();
    if (tid == 0) {
        int r = 0;
        #pragma unroll
        for (int i = 0; i < 4; ++i) { int c = wsum[i]; wsum[i] = r; r += c; }
    }
    __syncthreads();
    const int base = part[blockIdx.x] + wsum[wv] + (incl - s);
    #pragma unroll
    for (int q = 0; q < 8; ++q) {
        int idx = tbase + q;
        if (idx < N) {
            int pos = base + local[q];
            rowptr[idx] = pos;
            int c0 = cnt[idx], c1 = cnt[N + idx], c2 = cnt[2 * N + idx];
            cnt[idx] = pos;
            cnt[N + idx] = pos + c0;
            cnt[2 * N + idx] = pos + c0 + c1;
            cnt[3 * N + idx] = pos + c0 + c1 + c2;
        }
    }
}

// ---- fused softmax + weighted gather. One wave/node, 4 groups x 16 lanes,
// 2-edge unrolled. No max pass (logits bounded; softmax shift-invariant).
// OUTBF: write bf16 (aggx). else: f32 + bias (final output).
template <bool OUTBF>
__global__ __launch_bounds__(256) void node_gather_k(
    const int* __restrict__ rowptr, const int* __restrict__ ssrc,
    const float* __restrict__ s, const float* __restrict__ d,
    const unsigned short* __restrict__ hsrc, const float* __restrict__ bias,
    unsigned short* __restrict__ obf, float* __restrict__ outf, int N) {
    constexpr int F = 128, G = 4;
    const int node = blockIdx.x * 4 + (threadIdx.x >> 6);
    const int lane = threadIdx.x & 63;
    if (node >= N) return;
    const int beg = rowptr[node];
    const int end = rowptr[node + 1];
    const float dn = d[node];
    const int grp = lane >> 4;   // 0..3
    const int lr = lane & 15;    // 0..15

    float acc[8] = {};
    float zsum = 0.f;
    int j = beg + grp;
    for (; j + G < end; j += 2 * G) {
        int sj0 = ssrc[j];
        int sj1 = ssrc[j + G];
        float e0 = s[sj0] + dn;
        float e1 = s[sj1] + dn;
        bf16x8 v0 = *(const bf16x8*)(hsrc + (size_t)sj0 * F + lr * 8);
        bf16x8 v1 = *(const bf16x8*)(hsrc + (size_t)sj1 * F + lr * 8);
        e0 = (e0 > 0.f) ? e0 : NEG_SLOPE * e0;
        e1 = (e1 > 0.f) ? e1 : NEG_SLOPE * e1;
        float x0 = __expf(e0);
        float x1 = __expf(e1);
        zsum += x0 + x1;
        #pragma unroll
        for (int q = 0; q < 8; ++q) {
            acc[q] += x0 * bf2f(((unsigned short*)&v0)[q]);
            acc[q] += x1 * bf2f(((unsigned short*)&v1)[q]);
        }
    }
    if (j < end) {
        int sj = ssrc[j];
        float e = s[sj] + dn;
        e = (e > 0.f) ? e : NEG_SLOPE * e;
        float exj = __expf(e);
        zsum += exj;
        bf16x8 v = *(const bf16x8*)(hsrc + (size_t)sj * F + lr * 8);
        #pragma unroll
        for (int q = 0; q < 8; ++q)
            acc[q] += exj * bf2f(((unsigned short*)&v)[q]);
    }
    #pragma unroll
    for (int off = 16; off < 64; off <<= 1) {
        zsum += __shfl_xor(zsum, off);
        #pragma unroll
        for (int q = 0; q < 8; ++q) acc[q] += __shfl_xor(acc[q], off);
    }
    const float inv = 1.f / zsum;

    if (lane < 16) {
        if constexpr (OUTBF) {
            bf16x8 w;
            #pragma unroll
            for (int q = 0; q < 8; ++q)
                ((unsigned short*)&w)[q] = f2bf(acc[q] * inv);
            *(bf16x8*)(obf + (size_t)node * F + lr * 8) = w;
        } else {
            float o[8];
            #pragma unroll
            for (int q = 0; q < 8; ++q)
                o[q] = acc[q] * inv + bias[lr * 8 + q];
            float* op = outf + (size_t)node * F + lr * 8;
            *(float4*)op = {o[0], o[1], o[2], o[3]};
            *(float4*)(op + 4) = {o[4], o[5], o[6], o[7]};
        }
    }
}

extern "C" void kernel_launch(void* const* d_in, const int* in_sizes, int n_in,
                              void* d_out, int out_size, void* d_ws, size_t ws_size,
                              hipStream_t stream) {
    const float* x      = (const float*)d_in[0];
    const int*   eidx   = (const int*)d_in[1];
    const float* W1     = (const float*)d_in[2];
    const float* a_src1 = (const float*)d_in[3];
    const float* a_dst1 = (const float*)d_in[4];
    const float* b1     = (const float*)d_in[5];
    const float* W2     = (const float*)d_in[6];
    const float* a_src2 = (const float*)d_in[7];
    const float* a_dst2 = (const float*)d_in[8];
    const float* b2     = (const float*)d_in[9];

    const int N = in_sizes[0] / 128;   // 50000
    const int E = in_sizes[1] / 2;     // 800000
    const int F_IN = 128, H = 256, F_OUT = 128;
    const int EA = E + N;

    const int* srcE = eidx;
    const int* dstE = eidx + E;

    // ---- workspace layout (~74 MB) ----
    unsigned short* xbf    = (unsigned short*)d_ws;                 // N*128 bf16
    unsigned short* aggx   = xbf + (size_t)N * F_IN;                // N*128 bf16
    unsigned short* g1     = aggx + (size_t)N * F_IN;               // N*256 bf16
    unsigned short* h2bf   = g1 + (size_t)N * H;                    // N*128 bf16
    float*          sbuf   = (float*)(h2bf + (size_t)N * F_OUT);    // N
    float*          dbuf   = sbuf + N;                              // N
    float*          w_s1   = dbuf + N;                              // 128
    float*          w_d1   = w_s1 + F_IN;                           // 128
    unsigned short* w1T    = (unsigned short*)(w_d1 + F_IN);        // 256*128
    unsigned short* w2T    = w1T + 32768;                           // 128*256
    int*            rowptr = (int*)(w2T + 32768);                   // N+1
    int*            cnt    = rowptr + (N + 1);                      // NREP*N
    int*            part   = cnt + NREP * N;                        // 32
    int*            ssrc   = part + 32;                             // E+N
    int*            rank   = ssrc + EA;                             // E+N

    float* out = (float*)d_out;

    // ---------------- CSR build ----------------
    {
        hipMemsetAsync(cnt, 0, (size_t)NREP * N * 4, stream);
        int stride = (EA + RANK_VPT - 1) / RANK_VPT;
        int rblocks = (stride + 255) / 256;
        stride = rblocks * 256;
        rank_k<<<rblocks, 256, 0, stream>>>(dstE, cnt, rank, E, N, stride);
        int nseg = (N + SCAN_SEG - 1) / SCAN_SEG;
        scan_part_k<<<nseg, 256, 0, stream>>>(cnt, part, N);
        scan_offsets_k<<<1, 64, 0, stream>>>(part, nseg, rowptr, N);
        scan_write_k<<<nseg, 256, 0, stream>>>(cnt, rowptr, part, N);
        place_k<<<rblocks, 256, 0, stream>>>(srcE, dstE, cnt, rank, ssrc, E, N, stride);
    }

    // ---------------- prep: transposes + projections (one kernel) ----------
    wprep_k<<<288, 256, 0, stream>>>(W1, W2, a_src1, a_dst1, w1T, w2T, w_s1, w_d1);

    // ---------------- layer 1: xprep -> gather(x) -> GEMM ----------------
    {
        int rb = (N * 64 + 255) / 256;
        xprep_k<<<rb, 256, 0, stream>>>(x, w_s1, w_d1, xbf, sbuf, dbuf, N);

        int nb = (N + 3) / 4;
        node_gather_k<true><<<nb, 256, 0, stream>>>(
            rowptr, ssrc, sbuf, dbuf, xbf, nullptr, aggx, nullptr, N);

        dim3 gg((N + 127) / 128, H / 128);
        gemm_bf16<128, 256, 1><<<gg, 256, 0, stream>>>(
            aggx, w1T, g1, b1, nullptr, nullptr, nullptr, nullptr, N);
    }

    // ---------------- layer 2: GEMM(+rowdots) -> gather(h2) ----------------
    {
        dim3 gg((N + 127) / 128, 1);
        gemm_bf16<256, 128, 2><<<gg, 256, 0, stream>>>(
            g1, w2T, h2bf, nullptr, a_src2, a_dst2, sbuf, dbuf, N);

        int nb = (N + 3) / 4;
        node_gather_k<false><<<nb, 256, 0, stream>>>(
            rowptr, ssrc, sbuf, dbuf, h2bf, b2, nullptr, out, N);
    }
}